// Round 6
// baseline (256.957 us; speedup 1.0000x reference)
//
#include <hip/hip_runtime.h>
#include <hip/hip_bf16.h>

// Problem constants
#define T_ 32
#define N_ 16
#define C_ 64
#define L_ 64
#define H_ 128
#define G3 384
#define TOT 323

// ws layout (float offsets).  X layout is [l or t][c(384)][n(16)]
#define OFF_XF 0
#define OFF_XB 393216
#define OFF_XG 786432
#define OFF_Q  983040
#define OFF_V  1048576
#define OFF_HS 1049088
// Kmat (bf16) byte offset: (OFF_HS + 65536)*4
#define KM_OFF 4458496

typedef __attribute__((ext_vector_type(8))) short s16x8;
typedef __attribute__((ext_vector_type(4))) short s16x4;
typedef __attribute__((ext_vector_type(4))) float fx4;

__device__ __forceinline__ unsigned short f2bf(float f) {
  unsigned u = __builtin_bit_cast(unsigned, f);
  unsigned r = (u + 0x7FFFu + ((u >> 16) & 1u)) >> 16;
  return (unsigned short)r;
}
__device__ __forceinline__ float bf2f(unsigned short u) {
  unsigned v = ((unsigned)u) << 16;
  return __builtin_bit_cast(float, v);
}
__device__ __forceinline__ float sigm(float x) {
  return __builtin_amdgcn_rcpf(1.f + __expf(-x));
}
__device__ __forceinline__ float tanh_(float x) {
  return 1.f - 2.f * __builtin_amdgcn_rcpf(__expf(2.f * x) + 1.f);
}

// ---------------------------------------------------------------------------
// pre: blocks [0,128): Xf/Xb[l] = gi @ Wih_d.T + bih_d  via MFMA  (l=bid>>1,d=bid&1)
//      blocks [128,160): XG[t] = aemb[a_prev[t]] @ gc_Wih.T + gc_bih via MFMA
//      blocks [160,288): 4 (t,n) MLPs per block (q_all / v_all, fp32)
// X stored as [c][n] (transposed) for coalesced mid reads.
// ---------------------------------------------------------------------------
__global__ __launch_bounds__(512) void pre_kernel(
    const float* __restrict__ cond, const int* __restrict__ lines,
    const int* __restrict__ given_a, const float* __restrict__ hx,
    const float* __restrict__ emb, const float* __restrict__ aemb,
    const float* __restrict__ Wih_f, const float* __restrict__ bih_f,
    const float* __restrict__ Wih_b, const float* __restrict__ bih_b,
    const float* __restrict__ gc_Wih, const float* __restrict__ gc_bih,
    const float* __restrict__ f_W0, const float* __restrict__ f_b0,
    const float* __restrict__ f_W1, const float* __restrict__ f_b1,
    const float* __restrict__ f_W2, const float* __restrict__ f_b2,
    const float* __restrict__ c_W0, const float* __restrict__ c_b0,
    const float* __restrict__ c_W1, const float* __restrict__ c_b1,
    const float* __restrict__ c_W2, const float* __restrict__ c_b2,
    float* __restrict__ wsf)
{
  __shared__ __align__(16) float xs[2048];
  const int bid = blockIdx.x, tid = threadIdx.x;

  if (bid < 160) {
    // ---- MFMA gate matmul: A = x(16 rows batch x 128) bf16 (LDS swizzled) ----
    unsigned short* xbf = (unsigned short*)xs;   // [16][128] bf16, XOR-swizzled
    const float* W; const float* bias; float* outp;
    {
      int n = tid >> 5, k4 = (tid & 31) * 4;
      const float* src;
      if (bid < 128) {
        int l = bid >> 1;
        int e = lines[n * L_ + l];
        src = emb + e * H_ + k4;
      } else {
        int t = bid - 128;
        int ap = (t == 0) ? (int)hx[n * TOT] : given_a[(t - 1) * N_ + n];
        src = aemb + ap * H_ + k4;
      }
      float4 v = *(const float4*)src;
      s16x4 pk;
      pk[0] = (short)f2bf(v.x); pk[1] = (short)f2bf(v.y);
      pk[2] = (short)f2bf(v.z); pk[3] = (short)f2bf(v.w);
      int byte = (n * 256 + k4 * 2) ^ ((n & 7) << 4);
      *(s16x4*)((char*)xbf + byte) = pk;
    }
    if (bid < 128) {
      int d = bid & 1, l = bid >> 1;
      W = d ? Wih_b : Wih_f;  bias = d ? bih_b : bih_f;
      outp = wsf + (d ? OFF_XB : OFF_XF) + l * (G3 * N_);
    } else {
      W = gc_Wih; bias = gc_bih;
      outp = wsf + OFF_XG + (bid - 128) * (G3 * N_);
    }
    __syncthreads();
    const int w = tid >> 6, lane = tid & 63;
    const int col16 = lane & 15, krow = lane >> 4, bq = krow * 4;
    s16x8 Af[4];
    #pragma unroll
    for (int kb = 0; kb < 4; ++kb) {
      int ab = (col16 * 256 + kb * 64 + krow * 16) ^ ((col16 & 7) << 4);
      Af[kb] = *(const s16x8*)((const char*)xbf + ab);
    }
    #pragma unroll
    for (int g = 0; g < 3; ++g) {
      int cg = (g * 8 + w) * 16 + col16;
      float bv = bias[cg];
      fx4 a; a[0] = bv; a[1] = bv; a[2] = bv; a[3] = bv;
      #pragma unroll
      for (int kb = 0; kb < 4; ++kb) {
        const float* src = W + cg * H_ + kb * 32 + krow * 8;
        float4 aa = *(const float4*)src;
        float4 bb = *(const float4*)(src + 4);
        s16x8 sv;
        sv[0] = (short)f2bf(aa.x); sv[1] = (short)f2bf(aa.y);
        sv[2] = (short)f2bf(aa.z); sv[3] = (short)f2bf(aa.w);
        sv[4] = (short)f2bf(bb.x); sv[5] = (short)f2bf(bb.y);
        sv[6] = (short)f2bf(bb.z); sv[7] = (short)f2bf(bb.w);
        a = __builtin_amdgcn_mfma_f32_16x16x32_bf16(Af[kb], sv, a, 0, 0, 0);
      }
      #pragma unroll
      for (int r = 0; r < 4; ++r)
        outp[cg * 16 + bq + r] = a[r];
    }
  } else {
    // ---- 4 per-(t,n) MLPs per block ----
    const int grp = tid >> 7, c = tid & 127;
    const int tn = (bid - 160) * 4 + grp;
    const int lane = c & 63, widg = c >> 6;
    float* x0 = xs + grp * 384;
    float* x1 = x0 + 128;
    float* x2 = x0 + 256;
    float* xred = xs + 1536;
    // q path
    if (c < 64) x0[c] = cond[tn * C_ + c];
    __syncthreads();
    {
      float a0 = f_b0[c], a1 = 0.f, a2 = 0.f, a3 = 0.f;
      #pragma unroll 4
      for (int k = 0; k < 64; k += 4) {
        a0 += x0[k] * f_W0[k * H_ + c];
        a1 += x0[k + 1] * f_W0[(k + 1) * H_ + c];
        a2 += x0[k + 2] * f_W0[(k + 2) * H_ + c];
        a3 += x0[k + 3] * f_W0[(k + 3) * H_ + c];
      }
      x1[c] = fmaxf((a0 + a1) + (a2 + a3), 0.f);
    }
    __syncthreads();
    {
      float a0 = f_b1[c], a1 = 0.f, a2 = 0.f, a3 = 0.f;
      #pragma unroll 4
      for (int k = 0; k < 128; k += 4) {
        a0 += x1[k] * f_W1[k * H_ + c];
        a1 += x1[k + 1] * f_W1[(k + 1) * H_ + c];
        a2 += x1[k + 2] * f_W1[(k + 2) * H_ + c];
        a3 += x1[k + 3] * f_W1[(k + 3) * H_ + c];
      }
      x2[c] = fmaxf((a0 + a1) + (a2 + a3), 0.f);
    }
    __syncthreads();
    {
      float a0 = f_b2[c], a1 = 0.f, a2 = 0.f, a3 = 0.f;
      #pragma unroll 4
      for (int k = 0; k < 128; k += 4) {
        a0 += x2[k] * f_W2[k * H_ + c];
        a1 += x2[k + 1] * f_W2[(k + 1) * H_ + c];
        a2 += x2[k + 2] * f_W2[(k + 2) * H_ + c];
        a3 += x2[k + 3] * f_W2[(k + 3) * H_ + c];
      }
      wsf[OFF_Q + tn * H_ + c] = fmaxf((a0 + a1) + (a2 + a3), 0.f);
    }
    __syncthreads();
    // v path
    if (c < 64) {
      x0[c] = cond[tn * C_ + c];
      x0[64 + c] = (float)lines[tn * L_ + c];
    }
    __syncthreads();
    {
      float a0 = c_b0[c], a1 = 0.f, a2 = 0.f, a3 = 0.f;
      #pragma unroll 4
      for (int k = 0; k < 128; k += 4) {
        a0 += x0[k] * c_W0[k * H_ + c];
        a1 += x0[k + 1] * c_W0[(k + 1) * H_ + c];
        a2 += x0[k + 2] * c_W0[(k + 2) * H_ + c];
        a3 += x0[k + 3] * c_W0[(k + 3) * H_ + c];
      }
      x1[c] = fmaxf((a0 + a1) + (a2 + a3), 0.f);
    }
    __syncthreads();
    {
      float a0 = c_b1[c], a1 = 0.f, a2 = 0.f, a3 = 0.f;
      #pragma unroll 4
      for (int k = 0; k < 128; k += 4) {
        a0 += x1[k] * c_W1[k * H_ + c];
        a1 += x1[k + 1] * c_W1[(k + 1) * H_ + c];
        a2 += x1[k + 2] * c_W1[(k + 2) * H_ + c];
        a3 += x1[k + 3] * c_W1[(k + 3) * H_ + c];
      }
      x2[c] = fmaxf((a0 + a1) + (a2 + a3), 0.f);
    }
    __syncthreads();
    {
      float pv = x2[c] * c_W2[c];
      #pragma unroll
      for (int off = 32; off; off >>= 1) pv += __shfl_xor(pv, off);
      if (lane == 0) xred[grp * 2 + widg] = pv;
    }
    __syncthreads();
    if (c == 0)
      wsf[OFF_V + tn] = c_b2[0] + xred[grp * 2] + xred[grp * 2 + 1];
  }
}

// ---------------------------------------------------------------------------
// mid: blocks [0,64): BOTH direction chains of roll i in one block.
//   waves 0-3: d=0 chain, waves 4-7: d=1 chain. Each wave: 2 h-col-tiles x
//   3 gates = 24 MFMA/step, Whh frags in regs, h bf16 in swizzled LDS dbuf.
//   Independent chains on the same SIMD overlap latencies between barriers.
//      blocks [64,80): gc-GRU chain, one per batch row n.
// ---------------------------------------------------------------------------
__global__ __launch_bounds__(512) void mid_kernel(
    const float* __restrict__ Whh_f, const float* __restrict__ Whh_b,
    const float* __restrict__ bhh_f, const float* __restrict__ bhh_b,
    const float* __restrict__ gc_Whh, const float* __restrict__ gc_bhh,
    const float* __restrict__ hx,
    float* __restrict__ wsf, unsigned short* __restrict__ Km)
{
  __shared__ __align__(16) unsigned short hls[8192];  // 16KB: [d][p][16][128]
  const int bid = blockIdx.x, tid = threadIdx.x;

  if (bid < 64) {
    const int i = bid;
    const int wv = tid >> 6, lane = tid & 63;
    const int d = wv >> 2, ws4 = wv & 3;
    const int col16 = lane & 15, krow = lane >> 4, bq = krow * 4;
    const float* Whh = d ? Whh_b : Whh_f;
    const float* bhh = d ? bhh_b : bhh_f;
    const float* Xd = wsf + (d ? OFF_XB : OFF_XF);

    for (int idx = tid; idx < 8192; idx += 512) hls[idx] = 0;

    // B fragments (Whh.T) for 6 col-gate tiles, bf16 in regs
    s16x8 Bf[3][2][4];
    float bias[3][2];
    int voff[3][2];
    #pragma unroll
    for (int g = 0; g < 3; ++g)
      #pragma unroll
      for (int tl = 0; tl < 2; ++tl) {
        int cg = g * 128 + ws4 * 32 + tl * 16 + col16;
        bias[g][tl] = bhh[cg];
        voff[g][tl] = cg * 16 + bq;
        #pragma unroll
        for (int kb = 0; kb < 4; ++kb) {
          const float* src = Whh + cg * H_ + kb * 32 + krow * 8;
          float4 aa = *(const float4*)src;
          float4 bb = *(const float4*)(src + 4);
          s16x8 sv;
          sv[0] = (short)f2bf(aa.x); sv[1] = (short)f2bf(aa.y);
          sv[2] = (short)f2bf(aa.z); sv[3] = (short)f2bf(aa.w);
          sv[4] = (short)f2bf(bb.x); sv[5] = (short)f2bf(bb.y);
          sv[6] = (short)f2bf(bb.z); sv[7] = (short)f2bf(bb.w);
          Bf[g][tl][kb] = sv;
        }
      }
    const int cc0 = ws4 * 32 + col16;
    const int jj0 = d ? 63 : 0;
    int koff[2][4];
    #pragma unroll
    for (int tl = 0; tl < 2; ++tl)
      #pragma unroll
      for (int r = 0; r < 4; ++r) {
        int b = bq + r, cc = cc0 + tl * 16;
        koff[tl][r] = (((b * 64 + i) * 128 + (2 * jj0 + d)) * 128 + cc) * 2;
      }
    const int kdel = d ? -512 : 512;
    float hreg[2][4] = {{0.f, 0.f, 0.f, 0.f}, {0.f, 0.f, 0.f, 0.f}};
    char* lb = (char*)hls + d * 8192;
    int lx = (jj0 - i) & 63;
    __syncthreads();

    // prologue: xp for step 0
    fx4 xpA[3][2], xpB[3][2];
    {
      const float* Xc = Xd + lx * (G3 * N_);
      #pragma unroll
      for (int g = 0; g < 3; ++g)
        #pragma unroll
        for (int tl = 0; tl < 2; ++tl)
          xpA[g][tl] = *(const fx4*)(Xc + voff[g][tl]);
    }

    auto STEP = [&](int p, fx4 (&XC)[3][2], fx4 (&XN)[3][2]) {
      // 1. ds_read A fragments (critical path first)
      s16x8 Af[4];
      #pragma unroll
      for (int kb = 0; kb < 4; ++kb) {
        int ab = (col16 * 256 + kb * 64 + krow * 16) ^ ((col16 & 7) << 4);
        Af[kb] = *(const s16x8*)(lb + p * 4096 + ab);
      }
      // 2. prefetch next step's x-parts (coalesced dwordx4)
      int lxn = (d ? (lx - 1) : (lx + 1)) & 63;
      {
        const float* Xn = Xd + lxn * (G3 * N_);
        #pragma unroll
        for (int g = 0; g < 3; ++g)
          #pragma unroll
          for (int tl = 0; tl < 2; ++tl)
            XN[g][tl] = *(const fx4*)(Xn + voff[g][tl]);
      }
      // 3. MFMA
      fx4 acc[3][2];
      #pragma unroll
      for (int g = 0; g < 3; ++g)
        #pragma unroll
        for (int tl = 0; tl < 2; ++tl) {
          float bv = bias[g][tl];
          fx4 a; a[0] = bv; a[1] = bv; a[2] = bv; a[3] = bv;
          #pragma unroll
          for (int kb = 0; kb < 4; ++kb)
            a = __builtin_amdgcn_mfma_f32_16x16x32_bf16(Af[kb], Bf[g][tl][kb], a, 0, 0, 0);
          acc[g][tl] = a;
        }
      // 4. gates + h update; ds_write first, then Km stores
      char* wb = lb + (p ^ 1) * 4096;
      unsigned short uu[2][4];
      #pragma unroll
      for (int tl = 0; tl < 2; ++tl) {
        int ccb = (cc0 + tl * 16) * 2;
        #pragma unroll
        for (int r = 0; r < 4; ++r) {
          int b = bq + r;
          float rr = sigm(XC[0][tl][r] + acc[0][tl][r]);
          float zz = sigm(XC[1][tl][r] + acc[1][tl][r]);
          float nn = tanh_(XC[2][tl][r] + rr * acc[2][tl][r]);
          float hn = nn + zz * (hreg[tl][r] - nn);
          hreg[tl][r] = hn;
          unsigned short u = f2bf(hn);
          uu[tl][r] = u;
          *(unsigned short*)(wb + ((b * 256 + ccb) ^ ((b & 7) << 4))) = u;
        }
      }
      #pragma unroll
      for (int tl = 0; tl < 2; ++tl)
        #pragma unroll
        for (int r = 0; r < 4; ++r) {
          *(unsigned short*)((char*)Km + koff[tl][r]) = uu[tl][r];
          koff[tl][r] += kdel;
        }
      // 5. lgkm-only barrier: Km stores + xp prefetch stay in flight
      asm volatile("s_waitcnt lgkmcnt(0)" ::: "memory");
      __builtin_amdgcn_s_barrier();
      asm volatile("" ::: "memory");
      lx = lxn;
    };

    #pragma unroll 1
    for (int it = 0; it < 32; ++it) {
      STEP(0, xpA, xpB);
      STEP(1, xpB, xpA);
    }
  } else {
    // gc-GRU chain for batch row n; gc_Whh row in registers
    const int n = bid - 64;
    float* hcur = (float*)hls;         // 128 f32
    float* gh = ((float*)hls) + 128;   // 384 f32
    float4 wreg[32];
    float bias_ = 0.f;
    if (tid < 384) {
      const float4* wr = (const float4*)(gc_Whh + tid * H_);
      #pragma unroll
      for (int k4 = 0; k4 < 32; ++k4) wreg[k4] = wr[k4];
      bias_ = gc_bhh[tid];
    }
    if (tid < 128) hcur[tid] = hx[n * TOT + 3 + tid];
    __syncthreads();
    #pragma unroll 1
    for (int t = 0; t < 32; ++t) {
      if (tid < 384) {
        float a0 = bias_, a1 = 0.f, a2 = 0.f, a3 = 0.f;
        const float4* hv = (const float4*)hcur;
        #pragma unroll
        for (int k4 = 0; k4 < 32; k4 += 4) {
          float4 w0 = wreg[k4],     h0 = hv[k4];
          float4 w1 = wreg[k4 + 1], h1 = hv[k4 + 1];
          float4 w2 = wreg[k4 + 2], h2 = hv[k4 + 2];
          float4 w3 = wreg[k4 + 3], h3 = hv[k4 + 3];
          a0 += w0.x * h0.x + w0.y * h0.y + w0.z * h0.z + w0.w * h0.w;
          a1 += w1.x * h1.x + w1.y * h1.y + w1.z * h1.z + w1.w * h1.w;
          a2 += w2.x * h2.x + w2.y * h2.y + w2.z * h2.z + w2.w * h2.w;
          a3 += w3.x * h3.x + w3.y * h3.y + w3.z * h3.z + w3.w * h3.w;
        }
        gh[tid] = (a0 + a1) + (a2 + a3);
      }
      __syncthreads();
      if (tid < 128) {
        const float* xgt = wsf + OFF_XG + t * (G3 * N_);
        float rr = sigm(xgt[tid * 16 + n] + gh[tid]);
        float zz = sigm(xgt[(128 + tid) * 16 + n] + gh[128 + tid]);
        float nn = tanh_(xgt[(256 + tid) * 16 + n] + rr * gh[256 + tid]);
        float hn = nn + zz * (hcur[tid] - nn);
        hcur[tid] = hn;
        wsf[OFF_HS + (t * N_ + n) * H_ + tid] = hn;
      }
      __syncthreads();
    }
  }
}

// ---------------------------------------------------------------------------
// post: one block per (t,n). a-MLP + p softmax, K-tile k.q + a softmax,
// assemble all 323 output columns (+ t==31 tail copy). OUTPUT IS FLOAT32.
// ---------------------------------------------------------------------------
__global__ __launch_bounds__(128) void post_kernel(
    const int* __restrict__ given_a, const int* __restrict__ given_p,
    const float* __restrict__ hx,
    const float* __restrict__ a_W0, const float* __restrict__ a_b0,
    const float* __restrict__ a_W1, const float* __restrict__ a_b1,
    const float* __restrict__ a_Wc, const float* __restrict__ a_bc,
    const float* __restrict__ wsf, const unsigned short* __restrict__ Km,
    float* __restrict__ out)
{
  __shared__ __align__(16) unsigned short ktile[16384];  // 32KB bf16, swizzled
  __shared__ float xa[128], xb2[128], qv[128], red[4];
  const int tn = blockIdx.x, t = tn >> 4, n = tn & 15;
  const int c = threadIdx.x;
  const int lane = c & 63, wid = c >> 6;

  // stage K[n][pt] tile, coalesced global -> swizzled LDS
  {
    int pt = given_p[tn];
    const s16x8* src = (const s16x8*)(Km + (n * 64 + pt) * 16384);
    #pragma unroll
    for (int it = 0; it < 16; ++it) {
      int chunk = it * 128 + c;
      s16x8 v = src[chunk];
      int byte = chunk * 16;
      int row = byte >> 8;
      *(s16x8*)((char*)ktile + (byte ^ ((row & 7) << 4))) = v;
    }
  }
  xa[c] = wsf[OFF_HS + tn * H_ + c];
  qv[c] = wsf[OFF_Q + tn * H_ + c];
  __syncthreads();
  // a-MLP
  float s = a_b0[c];
  #pragma unroll 8
  for (int k = 0; k < 128; ++k) s += xa[k] * a_W0[k * H_ + c];
  xb2[c] = fmaxf(s, 0.f);
  __syncthreads();
  s = a_b1[c];
  #pragma unroll 8
  for (int k = 0; k < 128; ++k) s += xb2[k] * a_W1[k * H_ + c];
  float x2v = fmaxf(s, 0.f);
  __syncthreads();
  xa[c] = x2v;
  __syncthreads();
  // a logits: k.q from swizzled LDS tile
  float al = 0.f;
  #pragma unroll
  for (int k8 = 0; k8 < 16; ++k8) {
    int byte = c * 256 + k8 * 16;
    s16x8 kv = *(const s16x8*)((const char*)ktile + (byte ^ ((c & 7) << 4)));
    #pragma unroll
    for (int j = 0; j < 8; ++j)
      al += bf2f((unsigned short)kv[j]) * qv[k8 * 8 + j];
  }
  // p logits (wave 0 only: 64 columns)
  float pl = 0.f;
  if (wid == 0) {
    float s2 = a_bc[lane];
    #pragma unroll 8
    for (int k = 0; k < 128; ++k) s2 += xa[k] * a_Wc[k * 64 + lane];
    pl = s2;
  }
  // a softmax over 128 (two waves + LDS combine)
  float m = al;
  #pragma unroll
  for (int off = 32; off; off >>= 1) m = fmaxf(m, __shfl_xor(m, off));
  if (lane == 0) red[wid] = m;
  __syncthreads();
  m = fmaxf(red[0], red[1]);
  float e = __expf(al - m);
  float ssum = e;
  #pragma unroll
  for (int off = 32; off; off >>= 1) ssum += __shfl_xor(ssum, off);
  if (lane == 0) red[2 + wid] = ssum;
  __syncthreads();
  float ap = e * __builtin_amdgcn_rcpf(red[2] + red[3]);

  const int obase = tn * TOT;
  const bool tail = (t == 31);
  const int tbase = 512 * TOT + n * TOT;
  // a_probs -> cols 131..258
  out[obase + 131 + c] = ap;
  if (tail) out[tbase + 131 + c] = ap;
  // h_rep -> cols 3..130
  {
    float hv = hx[n * TOT + 3 + c];
    out[obase + 3 + c] = hv;
    if (tail) out[tbase + 3 + c] = hv;
  }
  // p_probs -> cols 259..322 (wave 0)
  if (wid == 0) {
    float pm = pl;
    #pragma unroll
    for (int off = 32; off; off >>= 1) pm = fmaxf(pm, __shfl_xor(pm, off));
    float pe = __expf(pl - pm);
    float ps = pe;
    #pragma unroll
    for (int off = 32; off; off >>= 1) ps += __shfl_xor(ps, off);
    float pp = pe * __builtin_amdgcn_rcpf(ps);
    out[obase + 259 + lane] = pp;
    if (tail) out[tbase + 259 + lane] = pp;
  }
  if (c == 0) {
    float u0 = (float)given_a[tn];
    float u1 = (float)given_p[tn];
    float u2 = wsf[OFF_V + tn];
    out[obase + 0] = u0; out[obase + 1] = u1; out[obase + 2] = u2;
    if (tail) { out[tbase + 0] = u0; out[tbase + 1] = u1; out[tbase + 2] = u2; }
  }
}

extern "C" void kernel_launch(void* const* d_in, const int* in_sizes, int n_in,
                              void* d_out, int out_size, void* d_ws, size_t ws_size,
                              hipStream_t stream) {
  const float* cond  = (const float*)d_in[0];
  const int*   lines = (const int*)d_in[1];
  const int*   ga    = (const int*)d_in[2];
  const int*   gp    = (const int*)d_in[3];
  const float* hx    = (const float*)d_in[4];
  const float* emb   = (const float*)d_in[5];
  const float* aemb  = (const float*)d_in[6];
  const float* Wih_f = (const float*)d_in[7];
  const float* Whh_f = (const float*)d_in[8];
  const float* Wih_b = (const float*)d_in[9];
  const float* Whh_b = (const float*)d_in[10];
  const float* gcWih = (const float*)d_in[11];
  const float* gcWhh = (const float*)d_in[12];
  const float* bih_f = (const float*)d_in[13];
  const float* bhh_f = (const float*)d_in[14];
  const float* bih_b = (const float*)d_in[15];
  const float* bhh_b = (const float*)d_in[16];
  const float* gcbih = (const float*)d_in[17];
  const float* gcbhh = (const float*)d_in[18];
  const float* f_W0 = (const float*)d_in[19]; const float* f_b0 = (const float*)d_in[20];
  const float* f_W1 = (const float*)d_in[21]; const float* f_b1 = (const float*)d_in[22];
  const float* f_W2 = (const float*)d_in[23]; const float* f_b2 = (const float*)d_in[24];
  const float* c_W0 = (const float*)d_in[25]; const float* c_b0 = (const float*)d_in[26];
  const float* c_W1 = (const float*)d_in[27]; const float* c_b1 = (const float*)d_in[28];
  const float* c_W2 = (const float*)d_in[29]; const float* c_b2 = (const float*)d_in[30];
  const float* a_W0 = (const float*)d_in[31]; const float* a_b0 = (const float*)d_in[32];
  const float* a_W1 = (const float*)d_in[33]; const float* a_b1 = (const float*)d_in[34];
  const float* a_Wc = (const float*)d_in[35]; const float* a_bc = (const float*)d_in[36];

  float* wsf = (float*)d_ws;
  unsigned short* Km = (unsigned short*)((char*)d_ws + KM_OFF);
  float* out = (float*)d_out;

  pre_kernel<<<288, 512, 0, stream>>>(cond, lines, ga, hx, emb, aemb,
      Wih_f, bih_f, Wih_b, bih_b, gcWih, gcbih,
      f_W0, f_b0, f_W1, f_b1, f_W2, f_b2,
      c_W0, c_b0, c_W1, c_b1, c_W2, c_b2, wsf);
  mid_kernel<<<80, 512, 0, stream>>>(Whh_f, Whh_b, bhh_f, bhh_b,
      gcWhh, gcbhh, hx, wsf, Km);
  post_kernel<<<512, 128, 0, stream>>>(ga, gp, hx,
      a_W0, a_b0, a_W1, a_b1, a_Wc, a_bc, wsf, Km, out);
}

// Round 7
// 216.380 us; speedup vs baseline: 1.1875x; 1.1875x over previous
//
#include <hip/hip_runtime.h>
#include <hip/hip_bf16.h>

// Problem constants
#define T_ 32
#define N_ 16
#define C_ 64
#define L_ 64
#define H_ 128
#define G3 384
#define TOT 323

// ws layout (float offsets).  X layout is [l or t][c(384)][n(16)]
#define OFF_XF 0
#define OFF_XB 393216
#define OFF_XG 786432
#define OFF_Q  983040
#define OFF_V  1048576
#define OFF_HS 1049088
// Kmat (bf16) byte offset: (OFF_HS + 65536)*4
#define KM_OFF 4458496

typedef __attribute__((ext_vector_type(8))) short s16x8;
typedef __attribute__((ext_vector_type(4))) short s16x4;
typedef __attribute__((ext_vector_type(4))) float fx4;

__device__ __forceinline__ unsigned short f2bf(float f) {
  unsigned u = __builtin_bit_cast(unsigned, f);
  unsigned r = (u + 0x7FFFu + ((u >> 16) & 1u)) >> 16;
  return (unsigned short)r;
}
__device__ __forceinline__ float bf2f(unsigned short u) {
  unsigned v = ((unsigned)u) << 16;
  return __builtin_bit_cast(float, v);
}
__device__ __forceinline__ float sigm(float x) {
  return __builtin_amdgcn_rcpf(1.f + __expf(-x));
}
__device__ __forceinline__ float tanh_(float x) {
  return 1.f - 2.f * __builtin_amdgcn_rcpf(__expf(2.f * x) + 1.f);
}

// ---------------------------------------------------------------------------
// pre: blocks [0,128): Xf/Xb[l] = gi @ Wih_d.T + bih_d  via MFMA  (l=bid>>1,d=bid&1)
//      blocks [128,160): XG[t] = aemb[a_prev[t]] @ gc_Wih.T + gc_bih via MFMA
//      blocks [160,288): 4 (t,n) MLPs per block (q_all / v_all, fp32)
// X stored as [c][n] (transposed) for coalesced mid reads; D rows contiguous
// in n -> single fx4 store per gate tile.
// ---------------------------------------------------------------------------
__global__ __launch_bounds__(512) void pre_kernel(
    const float* __restrict__ cond, const int* __restrict__ lines,
    const int* __restrict__ given_a, const float* __restrict__ hx,
    const float* __restrict__ emb, const float* __restrict__ aemb,
    const float* __restrict__ Wih_f, const float* __restrict__ bih_f,
    const float* __restrict__ Wih_b, const float* __restrict__ bih_b,
    const float* __restrict__ gc_Wih, const float* __restrict__ gc_bih,
    const float* __restrict__ f_W0, const float* __restrict__ f_b0,
    const float* __restrict__ f_W1, const float* __restrict__ f_b1,
    const float* __restrict__ f_W2, const float* __restrict__ f_b2,
    const float* __restrict__ c_W0, const float* __restrict__ c_b0,
    const float* __restrict__ c_W1, const float* __restrict__ c_b1,
    const float* __restrict__ c_W2, const float* __restrict__ c_b2,
    float* __restrict__ wsf)
{
  __shared__ __align__(16) float xs[2048];
  const int bid = blockIdx.x, tid = threadIdx.x;

  if (bid < 160) {
    // ---- MFMA gate matmul: A = x(16 batch x 128) bf16 (LDS swizzled) ----
    unsigned short* xbf = (unsigned short*)xs;   // [16][128] bf16, XOR-swizzled
    const float* W; const float* bias; float* outp;
    {
      int n = tid >> 5, k4 = (tid & 31) * 4;
      const float* src;
      if (bid < 128) {
        int l = bid >> 1;
        int e = lines[n * L_ + l];
        src = emb + e * H_ + k4;
      } else {
        int t = bid - 128;
        int ap = (t == 0) ? (int)hx[n * TOT] : given_a[(t - 1) * N_ + n];
        src = aemb + ap * H_ + k4;
      }
      float4 v = *(const float4*)src;
      s16x4 pk;
      pk[0] = (short)f2bf(v.x); pk[1] = (short)f2bf(v.y);
      pk[2] = (short)f2bf(v.z); pk[3] = (short)f2bf(v.w);
      int byte = (n * 256 + k4 * 2) ^ ((n & 7) << 4);
      *(s16x4*)((char*)xbf + byte) = pk;
    }
    if (bid < 128) {
      int d = bid & 1, l = bid >> 1;
      W = d ? Wih_b : Wih_f;  bias = d ? bih_b : bih_f;
      outp = wsf + (d ? OFF_XB : OFF_XF) + l * (G3 * N_);
    } else {
      W = gc_Wih; bias = gc_bih;
      outp = wsf + OFF_XG + (bid - 128) * (G3 * N_);
    }
    __syncthreads();
    const int w = tid >> 6, lane = tid & 63;
    const int col16 = lane & 15, krow = lane >> 4, bq = krow * 4;
    s16x8 Af[4];
    #pragma unroll
    for (int kb = 0; kb < 4; ++kb) {
      int ab = (col16 * 256 + kb * 64 + krow * 16) ^ ((col16 & 7) << 4);
      Af[kb] = *(const s16x8*)((const char*)xbf + ab);
    }
    #pragma unroll
    for (int g = 0; g < 3; ++g) {
      int cg = (g * 8 + w) * 16 + col16;
      float bv = bias[cg];
      fx4 a; a[0] = bv; a[1] = bv; a[2] = bv; a[3] = bv;
      #pragma unroll
      for (int kb = 0; kb < 4; ++kb) {
        const float* src = W + cg * H_ + kb * 32 + krow * 8;
        float4 aa = *(const float4*)src;
        float4 bb = *(const float4*)(src + 4);
        s16x8 sv;
        sv[0] = (short)f2bf(aa.x); sv[1] = (short)f2bf(aa.y);
        sv[2] = (short)f2bf(aa.z); sv[3] = (short)f2bf(aa.w);
        sv[4] = (short)f2bf(bb.x); sv[5] = (short)f2bf(bb.y);
        sv[6] = (short)f2bf(bb.z); sv[7] = (short)f2bf(bb.w);
        a = __builtin_amdgcn_mfma_f32_16x16x32_bf16(Af[kb], sv, a, 0, 0, 0);
      }
      *(fx4*)(outp + cg * 16 + bq) = a;   // rows (n) contiguous in [c][n]
    }
  } else {
    // ---- 4 per-(t,n) MLPs per block ----
    const int grp = tid >> 7, c = tid & 127;
    const int tn = (bid - 160) * 4 + grp;
    const int lane = c & 63, widg = c >> 6;
    float* x0 = xs + grp * 384;
    float* x1 = x0 + 128;
    float* x2 = x0 + 256;
    float* xred = xs + 1536;
    // q path
    if (c < 64) x0[c] = cond[tn * C_ + c];
    __syncthreads();
    {
      float a0 = f_b0[c], a1 = 0.f, a2 = 0.f, a3 = 0.f;
      #pragma unroll 4
      for (int k = 0; k < 64; k += 4) {
        a0 += x0[k] * f_W0[k * H_ + c];
        a1 += x0[k + 1] * f_W0[(k + 1) * H_ + c];
        a2 += x0[k + 2] * f_W0[(k + 2) * H_ + c];
        a3 += x0[k + 3] * f_W0[(k + 3) * H_ + c];
      }
      x1[c] = fmaxf((a0 + a1) + (a2 + a3), 0.f);
    }
    __syncthreads();
    {
      float a0 = f_b1[c], a1 = 0.f, a2 = 0.f, a3 = 0.f;
      #pragma unroll 4
      for (int k = 0; k < 128; k += 4) {
        a0 += x1[k] * f_W1[k * H_ + c];
        a1 += x1[k + 1] * f_W1[(k + 1) * H_ + c];
        a2 += x1[k + 2] * f_W1[(k + 2) * H_ + c];
        a3 += x1[k + 3] * f_W1[(k + 3) * H_ + c];
      }
      x2[c] = fmaxf((a0 + a1) + (a2 + a3), 0.f);
    }
    __syncthreads();
    {
      float a0 = f_b2[c], a1 = 0.f, a2 = 0.f, a3 = 0.f;
      #pragma unroll 4
      for (int k = 0; k < 128; k += 4) {
        a0 += x2[k] * f_W2[k * H_ + c];
        a1 += x2[k + 1] * f_W2[(k + 1) * H_ + c];
        a2 += x2[k + 2] * f_W2[(k + 2) * H_ + c];
        a3 += x2[k + 3] * f_W2[(k + 3) * H_ + c];
      }
      wsf[OFF_Q + tn * H_ + c] = fmaxf((a0 + a1) + (a2 + a3), 0.f);
    }
    __syncthreads();
    // v path
    if (c < 64) {
      x0[c] = cond[tn * C_ + c];
      x0[64 + c] = (float)lines[tn * L_ + c];
    }
    __syncthreads();
    {
      float a0 = c_b0[c], a1 = 0.f, a2 = 0.f, a3 = 0.f;
      #pragma unroll 4
      for (int k = 0; k < 128; k += 4) {
        a0 += x0[k] * c_W0[k * H_ + c];
        a1 += x0[k + 1] * c_W0[(k + 1) * H_ + c];
        a2 += x0[k + 2] * c_W0[(k + 2) * H_ + c];
        a3 += x0[k + 3] * c_W0[(k + 3) * H_ + c];
      }
      x1[c] = fmaxf((a0 + a1) + (a2 + a3), 0.f);
    }
    __syncthreads();
    {
      float a0 = c_b1[c], a1 = 0.f, a2 = 0.f, a3 = 0.f;
      #pragma unroll 4
      for (int k = 0; k < 128; k += 4) {
        a0 += x1[k] * c_W1[k * H_ + c];
        a1 += x1[k + 1] * c_W1[(k + 1) * H_ + c];
        a2 += x1[k + 2] * c_W1[(k + 2) * H_ + c];
        a3 += x1[k + 3] * c_W1[(k + 3) * H_ + c];
      }
      x2[c] = fmaxf((a0 + a1) + (a2 + a3), 0.f);
    }
    __syncthreads();
    {
      float pv = x2[c] * c_W2[c];
      #pragma unroll
      for (int off = 32; off; off >>= 1) pv += __shfl_xor(pv, off);
      if (lane == 0) xred[grp * 2 + widg] = pv;
    }
    __syncthreads();
    if (c == 0)
      wsf[OFF_V + tn] = c_b2[0] + xred[grp * 2] + xred[grp * 2 + 1];
  }
}

// ---------------------------------------------------------------------------
// mid: blocks [0,128): one (roll i, dir d) GRU chain (round-5 winner shape).
//   8 waves; wave w owns gate columns [16w,16w+16) of r/z/n: 12 MFMA/step.
//   Whh frags in regs; h bf16 in XOR-swizzled LDS dbuf; lgkm-only barrier;
//   xp as 3 coalesced fx4 loads from transposed X; Km offsets incremental.
//      blocks [128,144): gc-GRU chain, one per batch row n.
// ---------------------------------------------------------------------------
__global__ __launch_bounds__(512) void mid_kernel(
    const float* __restrict__ Whh_f, const float* __restrict__ Whh_b,
    const float* __restrict__ bhh_f, const float* __restrict__ bhh_b,
    const float* __restrict__ gc_Whh, const float* __restrict__ gc_bhh,
    const float* __restrict__ hx,
    float* __restrict__ wsf, unsigned short* __restrict__ Km)
{
  __shared__ __align__(16) unsigned short hls[4096];  // 8KB: 2 x [16][128] bf16
  const int bid = blockIdx.x, tid = threadIdx.x;

  if (bid < 128) {
    const int i = bid >> 1, d = bid & 1;
    const float* Whh = d ? Whh_b : Whh_f;
    const float* bhh = d ? bhh_b : bhh_f;
    const float* Xd = wsf + (d ? OFF_XB : OFF_XF);
    const int w = tid >> 6, lane = tid & 63;
    const int col16 = lane & 15, krow = lane >> 4, bq = krow * 4;
    const int cc = w * 16 + col16;

    for (int idx = tid; idx < 4096; idx += 512) hls[idx] = 0;

    // B fragments (Whh.T) in regs, bf16
    s16x8 Bf[3][4];
    float bias[3];
    int voff[3];
    #pragma unroll
    for (int g = 0; g < 3; ++g) {
      int cg = (g * 8 + w) * 16 + col16;
      bias[g] = bhh[cg];
      voff[g] = cg * 16 + bq;
      #pragma unroll
      for (int kb = 0; kb < 4; ++kb) {
        const float* src = Whh + cg * H_ + kb * 32 + krow * 8;
        float4 aa = *(const float4*)src;
        float4 bb = *(const float4*)(src + 4);
        s16x8 sv;
        sv[0] = (short)f2bf(aa.x); sv[1] = (short)f2bf(aa.y);
        sv[2] = (short)f2bf(aa.z); sv[3] = (short)f2bf(aa.w);
        sv[4] = (short)f2bf(bb.x); sv[5] = (short)f2bf(bb.y);
        sv[6] = (short)f2bf(bb.z); sv[7] = (short)f2bf(bb.w);
        Bf[g][kb] = sv;
      }
    }
    const int jj0 = d ? 63 : 0;
    int koff[4];
    #pragma unroll
    for (int r = 0; r < 4; ++r)
      koff[r] = ((((bq + r) * 64 + i) * 128 + (2 * jj0 + d)) * 128 + cc) * 2;
    const int kdel = d ? -512 : 512;
    float hreg[4] = {0.f, 0.f, 0.f, 0.f};
    char* lbase = (char*)hls;
    int lx = (jj0 - i) & 63;
    __syncthreads();

    fx4 xpA[3], xpB[3];
    {
      const float* Xc = Xd + lx * (G3 * N_);
      #pragma unroll
      for (int g = 0; g < 3; ++g) xpA[g] = *(const fx4*)(Xc + voff[g]);
    }

    auto STEP = [&](int p, fx4 (&XC)[3], fx4 (&XN)[3]) {
      // 1. ds_read A fragments (critical path first)
      s16x8 Af[4];
      #pragma unroll
      for (int kb = 0; kb < 4; ++kb) {
        int ab = (col16 * 256 + kb * 64 + krow * 16) ^ ((col16 & 7) << 4);
        Af[kb] = *(const s16x8*)(lbase + p * 4096 + ab);
      }
      // 2. prefetch next step's x-parts (coalesced fx4)
      int lxn = (d ? (lx - 1) : (lx + 1)) & 63;
      {
        const float* Xn = Xd + lxn * (G3 * N_);
        #pragma unroll
        for (int g = 0; g < 3; ++g) XN[g] = *(const fx4*)(Xn + voff[g]);
      }
      // 3. MFMA
      fx4 acc[3];
      #pragma unroll
      for (int g = 0; g < 3; ++g) {
        float bv = bias[g];
        fx4 a; a[0] = bv; a[1] = bv; a[2] = bv; a[3] = bv;
        #pragma unroll
        for (int kb = 0; kb < 4; ++kb)
          a = __builtin_amdgcn_mfma_f32_16x16x32_bf16(Af[kb], Bf[g][kb], a, 0, 0, 0);
        acc[g] = a;
      }
      // 4. gates + h update; ds_write then Km store (incremental offset)
      char* wbb = lbase + (p ^ 1) * 4096;
      #pragma unroll
      for (int r = 0; r < 4; ++r) {
        int b = bq + r;
        float rr = sigm(XC[0][r] + acc[0][r]);
        float zz = sigm(XC[1][r] + acc[1][r]);
        float nn = tanh_(XC[2][r] + rr * acc[2][r]);
        float hn = nn + zz * (hreg[r] - nn);
        hreg[r] = hn;
        unsigned short u = f2bf(hn);
        *(unsigned short*)(wbb + ((b * 256 + cc * 2) ^ ((b & 7) << 4))) = u;
        *(unsigned short*)((char*)Km + koff[r]) = u;
        koff[r] += kdel;
      }
      // 5. lgkm-only barrier: Km stores + xp prefetch stay in flight
      asm volatile("s_waitcnt lgkmcnt(0)" ::: "memory");
      __builtin_amdgcn_s_barrier();
      asm volatile("" ::: "memory");
      lx = lxn;
    };

    #pragma unroll 1
    for (int it = 0; it < 32; ++it) {
      STEP(0, xpA, xpB);
      STEP(1, xpB, xpA);
    }
  } else {
    // gc-GRU chain for batch row n; gc_Whh row in registers
    const int n = bid - 128;
    float* hcur = (float*)hls;         // 128 f32
    float* gh = ((float*)hls) + 128;   // 384 f32
    float4 wreg[32];
    float bias_ = 0.f;
    if (tid < 384) {
      const float4* wr = (const float4*)(gc_Whh + tid * H_);
      #pragma unroll
      for (int k4 = 0; k4 < 32; ++k4) wreg[k4] = wr[k4];
      bias_ = gc_bhh[tid];
    }
    if (tid < 128) hcur[tid] = hx[n * TOT + 3 + tid];
    __syncthreads();
    #pragma unroll 1
    for (int t = 0; t < 32; ++t) {
      if (tid < 384) {
        float a0 = bias_, a1 = 0.f, a2 = 0.f, a3 = 0.f;
        const float4* hv = (const float4*)hcur;
        #pragma unroll
        for (int k4 = 0; k4 < 32; k4 += 4) {
          float4 w0 = wreg[k4],     h0 = hv[k4];
          float4 w1 = wreg[k4 + 1], h1 = hv[k4 + 1];
          float4 w2 = wreg[k4 + 2], h2 = hv[k4 + 2];
          float4 w3 = wreg[k4 + 3], h3 = hv[k4 + 3];
          a0 += w0.x * h0.x + w0.y * h0.y + w0.z * h0.z + w0.w * h0.w;
          a1 += w1.x * h1.x + w1.y * h1.y + w1.z * h1.z + w1.w * h1.w;
          a2 += w2.x * h2.x + w2.y * h2.y + w2.z * h2.z + w2.w * h2.w;
          a3 += w3.x * h3.x + w3.y * h3.y + w3.z * h3.z + w3.w * h3.w;
        }
        gh[tid] = (a0 + a1) + (a2 + a3);
      }
      __syncthreads();
      if (tid < 128) {
        const float* xgt = wsf + OFF_XG + t * (G3 * N_);
        float rr = sigm(xgt[tid * 16 + n] + gh[tid]);
        float zz = sigm(xgt[(128 + tid) * 16 + n] + gh[128 + tid]);
        float nn = tanh_(xgt[(256 + tid) * 16 + n] + rr * gh[256 + tid]);
        float hn = nn + zz * (hcur[tid] - nn);
        hcur[tid] = hn;
        wsf[OFF_HS + (t * N_ + n) * H_ + tid] = hn;
      }
      __syncthreads();
    }
  }
}

// ---------------------------------------------------------------------------
// post: one block per (t,n). a-logits dot DIRECT from global (K rows are
// single-use -> no LDS staging); a-MLP + softmaxes; assemble 323 output
// columns (+ t==31 tail copy). OUTPUT IS FLOAT32.
// ---------------------------------------------------------------------------
__global__ __launch_bounds__(128) void post_kernel(
    const int* __restrict__ given_a, const int* __restrict__ given_p,
    const float* __restrict__ hx,
    const float* __restrict__ a_W0, const float* __restrict__ a_b0,
    const float* __restrict__ a_W1, const float* __restrict__ a_b1,
    const float* __restrict__ a_Wc, const float* __restrict__ a_bc,
    const float* __restrict__ wsf, const unsigned short* __restrict__ Km,
    float* __restrict__ out)
{
  __shared__ float xa[128], xb2[128], qv[128], red[4];
  const int tn = blockIdx.x, t = tn >> 4, n = tn & 15;
  const int c = threadIdx.x;
  const int lane = c & 63, wid = c >> 6;

  const int pt = given_p[tn];
  const unsigned short* krow_ = Km + ((n * 64 + pt) * 128 + c) * 128;

  xa[c] = wsf[OFF_HS + tn * H_ + c];
  qv[c] = wsf[OFF_Q + tn * H_ + c];
  __syncthreads();

  // a logits: thread c dots K row c (128 bf16, 16x s16x8 global loads)
  float al = 0.f;
  #pragma unroll
  for (int k8 = 0; k8 < 16; ++k8) {
    s16x8 kv = *(const s16x8*)(krow_ + k8 * 8);
    #pragma unroll
    for (int j = 0; j < 8; ++j)
      al += bf2f((unsigned short)kv[j]) * qv[k8 * 8 + j];
  }

  // a-MLP
  float s = a_b0[c];
  #pragma unroll 8
  for (int k = 0; k < 128; ++k) s += xa[k] * a_W0[k * H_ + c];
  xb2[c] = fmaxf(s, 0.f);
  __syncthreads();
  s = a_b1[c];
  #pragma unroll 8
  for (int k = 0; k < 128; ++k) s += xb2[k] * a_W1[k * H_ + c];
  float x2v = fmaxf(s, 0.f);
  __syncthreads();
  xa[c] = x2v;
  __syncthreads();
  // p logits (wave 0 only: 64 columns)
  float pl = 0.f;
  if (wid == 0) {
    float s2 = a_bc[lane];
    #pragma unroll 8
    for (int k = 0; k < 128; ++k) s2 += xa[k] * a_Wc[k * 64 + lane];
    pl = s2;
  }
  // a softmax over 128 (two waves + LDS combine)
  float m = al;
  #pragma unroll
  for (int off = 32; off; off >>= 1) m = fmaxf(m, __shfl_xor(m, off));
  if (lane == 0) red[wid] = m;
  __syncthreads();
  m = fmaxf(red[0], red[1]);
  float e = __expf(al - m);
  float ssum = e;
  #pragma unroll
  for (int off = 32; off; off >>= 1) ssum += __shfl_xor(ssum, off);
  if (lane == 0) red[2 + wid] = ssum;
  __syncthreads();
  float ap = e * __builtin_amdgcn_rcpf(red[2] + red[3]);

  const int obase = tn * TOT;
  const bool tail = (t == 31);
  const int tbase = 512 * TOT + n * TOT;
  // a_probs -> cols 131..258
  out[obase + 131 + c] = ap;
  if (tail) out[tbase + 131 + c] = ap;
  // h_rep -> cols 3..130
  {
    float hv = hx[n * TOT + 3 + c];
    out[obase + 3 + c] = hv;
    if (tail) out[tbase + 3 + c] = hv;
  }
  // p_probs -> cols 259..322 (wave 0)
  if (wid == 0) {
    float pm = pl;
    #pragma unroll
    for (int off = 32; off; off >>= 1) pm = fmaxf(pm, __shfl_xor(pm, off));
    float pe = __expf(pl - pm);
    float ps = pe;
    #pragma unroll
    for (int off = 32; off; off >>= 1) ps += __shfl_xor(ps, off);
    float pp = pe * __builtin_amdgcn_rcpf(ps);
    out[obase + 259 + lane] = pp;
    if (tail) out[tbase + 259 + lane] = pp;
  }
  if (c == 0) {
    float u0 = (float)given_a[tn];
    float u1 = (float)given_p[tn];
    float u2 = wsf[OFF_V + tn];
    out[obase + 0] = u0; out[obase + 1] = u1; out[obase + 2] = u2;
    if (tail) { out[tbase + 0] = u0; out[tbase + 1] = u1; out[tbase + 2] = u2; }
  }
}

extern "C" void kernel_launch(void* const* d_in, const int* in_sizes, int n_in,
                              void* d_out, int out_size, void* d_ws, size_t ws_size,
                              hipStream_t stream) {
  const float* cond  = (const float*)d_in[0];
  const int*   lines = (const int*)d_in[1];
  const int*   ga    = (const int*)d_in[2];
  const int*   gp    = (const int*)d_in[3];
  const float* hx    = (const float*)d_in[4];
  const float* emb   = (const float*)d_in[5];
  const float* aemb  = (const float*)d_in[6];
  const float* Wih_f = (const float*)d_in[7];
  const float* Whh_f = (const float*)d_in[8];
  const float* Wih_b = (const float*)d_in[9];
  const float* Whh_b = (const float*)d_in[10];
  const float* gcWih = (const float*)d_in[11];
  const float* gcWhh = (const float*)d_in[12];
  const float* bih_f = (const float*)d_in[13];
  const float* bhh_f = (const float*)d_in[14];
  const float* bih_b = (const float*)d_in[15];
  const float* bhh_b = (const float*)d_in[16];
  const float* gcbih = (const float*)d_in[17];
  const float* gcbhh = (const float*)d_in[18];
  const float* f_W0 = (const float*)d_in[19]; const float* f_b0 = (const float*)d_in[20];
  const float* f_W1 = (const float*)d_in[21]; const float* f_b1 = (const float*)d_in[22];
  const float* f_W2 = (const float*)d_in[23]; const float* f_b2 = (const float*)d_in[24];
  const float* c_W0 = (const float*)d_in[25]; const float* c_b0 = (const float*)d_in[26];
  const float* c_W1 = (const float*)d_in[27]; const float* c_b1 = (const float*)d_in[28];
  const float* c_W2 = (const float*)d_in[29]; const float* c_b2 = (const float*)d_in[30];
  const float* a_W0 = (const float*)d_in[31]; const float* a_b0 = (const float*)d_in[32];
  const float* a_W1 = (const float*)d_in[33]; const float* a_b1 = (const float*)d_in[34];
  const float* a_Wc = (const float*)d_in[35]; const float* a_bc = (const float*)d_in[36];

  float* wsf = (float*)d_ws;
  unsigned short* Km = (unsigned short*)((char*)d_ws + KM_OFF);
  float* out = (float*)d_out;

  pre_kernel<<<288, 512, 0, stream>>>(cond, lines, ga, hx, emb, aemb,
      Wih_f, bih_f, Wih_b, bih_b, gcWih, gcbih,
      f_W0, f_b0, f_W1, f_b1, f_W2, f_b2,
      c_W0, c_b0, c_W1, c_b1, c_W2, c_b2, wsf);
  mid_kernel<<<144, 512, 0, stream>>>(Whh_f, Whh_b, bhh_f, bhh_b,
      gcWhh, gcbhh, hx, wsf, Km);
  post_kernel<<<512, 128, 0, stream>>>(ga, gp, hx,
      a_W0, a_b0, a_W1, a_b1, a_Wc, a_bc, wsf, Km, out);
}